// Round 5
// baseline (425.356 us; speedup 1.0000x reference)
//
#include <hip/hip_runtime.h>
#include <hip/hip_bf16.h>

// QJLSketch: H=32, G=128, N=64, D=128, S=256, K=8
// d_out (float32, concatenated):
//   [0,        8388608): hash_inlier  [32,128,64,32] byte values as floats
//   [8388608, 12582912): hash_outlier [32,128,64,16] byte values as floats
//   [12582912,12845056): scores       [32, 128*64]
//
// Strategy: bf16 hi/lo split MFMA GEMM (fast approx) + exact f32-chain fixup for
// |value| < EPS. Non-flagged signs provably match the reference's sequential
// f32 FMA chain; flagged ones are recomputed with R3's verified chain semantics.
// R5: slot-ordered A staging (conflict-free ds_write_b128), outlier fragments
// gathered per-lane into registers (no Ao/Bo LDS) -> LDS 54->33.8 KB, 4 blk/CU.

typedef __attribute__((ext_vector_type(8))) short short8;
typedef __attribute__((ext_vector_type(4))) float f32x4;

constexpr int cH = 32, cG = 128, cN = 64, cD = 128, cS = 256, cK = 8;
constexpr int HASH_OUT_BASE = cH * cG * cN * (cS / 8);                  // 8388608
constexpr int SCORE_BASE    = HASH_OUT_BASE + cH * cG * cN * (cS / 16); // 12582912
constexpr float EPS_IN  = 3e-3f;
constexpr float EPS_OUT = 5e-4f;
constexpr size_t WS_BHI = 32768, WS_BLO = 98304, WS_NEED = 163840;

#define MFMA(a, b, c) __builtin_amdgcn_mfma_f32_16x16x32_bf16(a, b, c, 0, 0, 0)

__device__ inline short f2bf(float x) {
    __hip_bfloat16 h = __float2bfloat16(x);            // RNE
    return __builtin_bit_cast(short, h);
}
__device__ inline float bf2f(short s) {
    return __bfloat162float(__builtin_bit_cast(__hip_bfloat16, s));
}
__device__ inline unsigned long long sel4(unsigned long long a0, unsigned long long a1,
                                          unsigned long long a2, unsigned long long a3, int r) {
    unsigned long long x = a0;
    x = (r == 1) ? a1 : x; x = (r == 2) ? a2 : x; x = (r == 3) ? a3 : x;
    return x;
}

// --- precompute: sketched_q[h][s] (sequential chain; scores have 2% tol) ---
__global__ __launch_bounds__(256) void qjl_qv(
    const float* __restrict__ query, const float* __restrict__ projs,
    float* __restrict__ qv_out)
{
    const int h = blockIdx.x, s = threadIdx.x;
    float qa = 0.0f;
    for (int d = 0; d < cD; ++d)
        qa = fmaf(query[h * cD + d], projs[d * cS + s], qa);
    qv_out[h * cS + s] = qa;
}

// --- precompute: B fragments (projq hi/lo bf16) in MFMA lane order ---
__global__ __launch_bounds__(256) void qjl_bfrag(
    const float* __restrict__ projq, short* __restrict__ bhi, short* __restrict__ blo)
{
    const int idx = blockIdx.x * 256 + threadIdx.x;    // [0, 4096)
    const int l = idx & 63, nt = (idx >> 6) & 15, ksub = idx >> 10;
    const int s = nt * 16 + (l & 15);
    const int k0 = ksub * 32 + (l >> 4) * 8;
    #pragma unroll
    for (int j = 0; j < 8; ++j) {
        float x = projq[s * cD + k0 + j];
        short h = f2bf(x);
        bhi[idx * 8 + j] = h;
        blo[idx * 8 + j] = f2bf(x - bf2f(h));
    }
}

__global__ __launch_bounds__(256) void qjl_mfma(
    const float* __restrict__ data, const int* __restrict__ oidx,
    const float* __restrict__ norm_data, const float* __restrict__ projq,
    const float* __restrict__ qv_ws, const short* __restrict__ bhi_ws,
    const short* __restrict__ blo_ws, float* __restrict__ out)
{
    const int b = blockIdx.x;        // h*G + g
    const int t = threadIdx.x;
    const int lane = t & 63;
    const int w = t >> 6;            // wave owns nt = 4w..4w+3 (s-range 64w..64w+63)
    const int h = b >> 7;

    __shared__ short A_hi[16 * 64 * 8];   // [frag=ksub*4+mt][lane][j]  16 KB
    __shared__ short A_lo[16 * 64 * 8];   // 16 KB
    __shared__ float ipPart[cN * 4];      // 1 KB

    // --- unique outlier indices, sorted (per-thread redundant) ---
    int u[cK]; int U = 0;
    for (int k = 0; k < cK; ++k) {
        int v = oidx[b * cK + k];
        bool dup = false;
        for (int j = 0; j < U; ++j) dup = dup || (u[j] == v);
        if (!dup) u[U++] = v;
    }
    for (int i = 1; i < U; ++i) {
        int key = u[i], j = i - 1;
        while (j >= 0 && u[j] > key) { u[j + 1] = u[j]; --j; }
        u[j + 1] = key;
    }
    unsigned long long m0 = 0, m1 = 0;
    for (int k = 0; k < U; ++k) {
        int v = u[k];
        if (v < 64) m0 |= 1ull << v; else m1 |= 1ull << (v - 64);
    }

    const float* __restrict__ chunk = data + (size_t)b * (cN * cD);

    // --- A staging: slot-ordered (frag = i*4 + w, l = lane) -> conflict-free ---
    #pragma unroll
    for (int i = 0; i < 4; ++i) {
        const int slot = i * 256 + t;        // frag = slot>>6, lane-within-frag = slot&63
        const int f = slot >> 6, l = slot & 63;
        const int mt = f & 3, ksub = f >> 2;
        const int row = mt * 16 + (l & 15);
        const int k0 = ksub * 32 + (l >> 4) * 8;
        const float4* p = reinterpret_cast<const float4*>(chunk + row * cD + k0);
        float4 v0 = p[0], v1 = p[1];
        float xs[8] = { v0.x, v0.y, v0.z, v0.w, v1.x, v1.y, v1.z, v1.w };
        short hs[8], ls[8];
        #pragma unroll
        for (int e = 0; e < 8; ++e) {
            hs[e] = f2bf(xs[e]);
            ls[e] = f2bf(xs[e] - bf2f(hs[e]));
        }
        *reinterpret_cast<short8*>(&A_hi[slot * 8]) =
            short8{ hs[0], hs[1], hs[2], hs[3], hs[4], hs[5], hs[6], hs[7] };
        *reinterpret_cast<short8*>(&A_lo[slot * 8]) =
            short8{ ls[0], ls[1], ls[2], ls[3], ls[4], ls[5], ls[6], ls[7] };
    }

    // --- outlier fragments per-lane in registers (replaces Ao/Bo LDS) ---
    // Ao K'=32 row-groups: [hi | hi | lo | 0] ; Bo: [hi | lo | hi | 0]
    const int krow = lane >> 4;
    short8 aO[4];
    #pragma unroll
    for (int mt = 0; mt < 4; ++mt) {
        const int row = mt * 16 + (lane & 15);
        short v8[8];
        #pragma unroll
        for (int k = 0; k < cK; ++k) {
            float x = (k < U && krow < 3) ? chunk[row * cD + u[k]] : 0.0f;
            short hi = f2bf(x);
            short lo = f2bf(x - bf2f(hi));
            v8[k] = (krow == 2) ? lo : ((krow == 3) ? (short)0 : hi);
        }
        aO[mt] = short8{ v8[0], v8[1], v8[2], v8[3], v8[4], v8[5], v8[6], v8[7] };
    }
    short8 bO[4];
    #pragma unroll
    for (int q = 0; q < 4; ++q) {
        const int s = (w * 4 + q) * 16 + (lane & 15);
        short v8[8];
        #pragma unroll
        for (int k = 0; k < cK; ++k) {
            float x = (k < U && krow < 3) ? projq[s * cD + u[k]] : 0.0f;
            short hi = f2bf(x);
            short lo = f2bf(x - bf2f(hi));
            v8[k] = (krow == 1) ? lo : ((krow == 3) ? (short)0 : hi);
        }
        bO[q] = short8{ v8[0], v8[1], v8[2], v8[3], v8[4], v8[5], v8[6], v8[7] };
    }

    f32x4 acc[16];
    const f32x4 zero4 = { 0.f, 0.f, 0.f, 0.f };

    // --- phase 1: outlier GEMM (sk_out approx) ---
    #pragma unroll
    for (int mt = 0; mt < 4; ++mt)
        #pragma unroll
        for (int q = 0; q < 4; ++q)
            acc[mt * 4 + q] = MFMA(aO[mt], bO[q], zero4);

    // --- phase 2: hash_outlier (s < 128 -> waves 0,1), with exact fixup ---
    if (w < 2) {
        #pragma unroll
        for (int mt = 0; mt < 4; ++mt) {
            #pragma unroll
            for (int q = 0; q < 4; ++q) {
                unsigned long long b0, b1, b2, b3;
                #pragma unroll
                for (int r = 0; r < 4; ++r) {
                    float v = acc[mt * 4 + q][r];
                    if (fabsf(v) < EPS_OUT) {
                        int row = mt * 16 + 4 * (lane >> 4) + r;
                        int s = (w * 4 + q) * 16 + (lane & 15);
                        const float* dr = chunk + row * cD;
                        const float* pr = projq + s * cD;
                        float o = 0.0f;
                        for (int k = 0; k < cK; ++k)
                            if (k < U) o = fmaf(dr[u[k]], pr[u[k]], o);
                        v = o;
                    }
                    unsigned long long bal = __ballot(v > 0.0f);
                    if (r == 0) b0 = bal; else if (r == 1) b1 = bal;
                    else if (r == 2) b2 = bal; else b3 = bal;
                }
                if (lane < 32) {
                    int r = lane & 3, g = (lane >> 2) & 3, hb = lane >> 4;
                    unsigned long long bb = sel4(b0, b1, b2, b3, r);
                    int row = mt * 16 + 4 * g + r;
                    out[HASH_OUT_BASE + (size_t)b * (cN * 16) + row * 16 + (w * 4 + q) * 2 + hb] =
                        (float)((bb >> (16 * g + 8 * hb)) & 0xFFull);
                }
            }
        }
    }

    // --- negate: acc becomes -sk_out, then accumulate full GEMM -> sk_in approx ---
    #pragma unroll
    for (int i = 0; i < 16; ++i)
        #pragma unroll
        for (int r = 0; r < 4; ++r)
            acc[i][r] = -acc[i][r];

    __syncthreads();   // A_hi/A_lo staged

    // --- phase 3: main GEMM, K' = 384 = [hi*Bhi | hi*Blo | lo*Bhi] ---
    #pragma unroll
    for (int ksub = 0; ksub < 4; ++ksub) {
        short8 a[4];
        #pragma unroll
        for (int mt = 0; mt < 4; ++mt)
            a[mt] = *reinterpret_cast<const short8*>(&A_hi[((ksub * 4 + mt) * 64 + lane) * 8]);
        #pragma unroll
        for (int q = 0; q < 4; ++q) {
            short8 bh = *reinterpret_cast<const short8*>(
                &bhi_ws[((ksub * 16 + w * 4 + q) * 64 + lane) * 8]);
            #pragma unroll
            for (int mt = 0; mt < 4; ++mt)
                acc[mt * 4 + q] = MFMA(a[mt], bh, acc[mt * 4 + q]);
        }
        #pragma unroll
        for (int q = 0; q < 4; ++q) {
            short8 bl = *reinterpret_cast<const short8*>(
                &blo_ws[((ksub * 16 + w * 4 + q) * 64 + lane) * 8]);
            #pragma unroll
            for (int mt = 0; mt < 4; ++mt)
                acc[mt * 4 + q] = MFMA(a[mt], bl, acc[mt * 4 + q]);
        }
    }
    #pragma unroll
    for (int ksub = 0; ksub < 4; ++ksub) {
        short8 a[4];
        #pragma unroll
        for (int mt = 0; mt < 4; ++mt)
            a[mt] = *reinterpret_cast<const short8*>(&A_lo[((ksub * 4 + mt) * 64 + lane) * 8]);
        #pragma unroll
        for (int q = 0; q < 4; ++q) {
            short8 bh = *reinterpret_cast<const short8*>(
                &bhi_ws[((ksub * 16 + w * 4 + q) * 64 + lane) * 8]);
            #pragma unroll
            for (int mt = 0; mt < 4; ++mt)
                acc[mt * 4 + q] = MFMA(a[mt], bh, acc[mt * 4 + q]);
        }
    }

    // --- phase 4: hash_inlier + ip partials, with exact-chain fixup ---
    float qvv[4];
    #pragma unroll
    for (int q = 0; q < 4; ++q)
        qvv[q] = qv_ws[h * cS + (w * 4 + q) * 16 + (lane & 15)];
    float part[4][4];
    #pragma unroll
    for (int mt = 0; mt < 4; ++mt)
        #pragma unroll
        for (int r = 0; r < 4; ++r) part[mt][r] = 0.0f;

    #pragma unroll
    for (int mt = 0; mt < 4; ++mt) {
        #pragma unroll
        for (int q = 0; q < 4; ++q) {
            unsigned long long b0, b1, b2, b3;
            #pragma unroll
            for (int r = 0; r < 4; ++r) {
                float v = acc[mt * 4 + q][r];
                if (fabsf(v) < EPS_IN) {
                    int row = mt * 16 + 4 * (lane >> 4) + r;
                    int s = (w * 4 + q) * 16 + (lane & 15);
                    const float* dr = chunk + row * cD;
                    const float* pr = projq + s * cD;
                    float ex = 0.0f;
                    for (int d = 0; d < cD; ++d) {
                        bool msk = ((((d < 64) ? (m0 >> d) : (m1 >> (d - 64))) & 1ull) != 0);
                        float pv = msk ? 0.0f : pr[d];
                        ex = fmaf(dr[d], pv, ex);
                    }
                    v = ex;
                }
                bool bit = v > 0.0f;
                unsigned long long bal = __ballot(bit);
                part[mt][r] += bit ? qvv[q] : -qvv[q];
                if (r == 0) b0 = bal; else if (r == 1) b1 = bal;
                else if (r == 2) b2 = bal; else b3 = bal;
            }
            if (lane < 32) {
                int r = lane & 3, g = (lane >> 2) & 3, hb = lane >> 4;
                unsigned long long bb = sel4(b0, b1, b2, b3, r);
                int row = mt * 16 + 4 * g + r;
                out[(size_t)b * (cN * 32) + row * 32 + (w * 4 + q) * 2 + hb] =
                    (float)((bb >> (16 * g + 8 * hb)) & 0xFFull);
            }
        }
    }

    // --- ip reduction: xor-tree over the 16 lanes sharing a row ---
    #pragma unroll
    for (int mt = 0; mt < 4; ++mt) {
        #pragma unroll
        for (int r = 0; r < 4; ++r) {
            float x = part[mt][r];
            x += __shfl_xor(x, 1); x += __shfl_xor(x, 2);
            x += __shfl_xor(x, 4); x += __shfl_xor(x, 8);
            if ((lane & 15) == 0)
                ipPart[(mt * 16 + 4 * (lane >> 4) + r) * 4 + w] = x;
        }
    }
    __syncthreads();
    if (t < cN) {
        float ip = ipPart[t * 4 + 0] + ipPart[t * 4 + 1]
                 + ipPart[t * 4 + 2] + ipPart[t * 4 + 3];
        const float scl = 0.0048957583f;   // sqrt(pi/2)/256
        out[SCORE_BASE + b * cN + t] = scl * norm_data[b * cN + t] * ip;
    }
}

// ---------------- fallback (R3 kernel, passed): used if ws too small ----------------
__global__ __launch_bounds__(256) void qjl_valu(
    const float* __restrict__ data, const float* __restrict__ query,
    const int* __restrict__ oidx, const float* __restrict__ norm_data,
    const float* __restrict__ projq, const float* __restrict__ projs,
    float* __restrict__ out)
{
    const int b2 = blockIdx.x, b = b2 >> 1, half = b2 & 1;
    const int t = threadIdx.x, lane = t & 63, w = t >> 6, h = b >> 7;
    __shared__ float ipPart[32 * 4];
    int u[cK]; int U = 0;
    for (int k = 0; k < cK; ++k) {
        int v = oidx[b * cK + k];
        bool dup = false;
        for (int j = 0; j < U; ++j) dup = dup || (u[j] == v);
        if (!dup) u[U++] = v;
    }
    for (int i = 1; i < U; ++i) {
        int key = u[i], j = i - 1;
        while (j >= 0 && u[j] > key) { u[j + 1] = u[j]; --j; }
        u[j + 1] = key;
    }
    unsigned long long m0 = 0, m1 = 0;
    for (int k = 0; k < U; ++k) {
        int v = u[k];
        if (v < 64) m0 |= 1ull << v; else m1 |= 1ull << (v - 64);
    }
    int ui[cK]; float prO[cK];
    #pragma unroll
    for (int k = 0; k < cK; ++k) ui[k] = (k < U) ? u[k] : 0;
    #pragma unroll
    for (int k = 0; k < cK; ++k) prO[k] = (k < U) ? projq[t * cD + ui[k]] : 0.0f;
    float qv = 0.0f;
    for (int d = 0; d < cD; ++d)
        qv = fmaf(query[h * cD + d], projs[d * cS + t], qv);
    const float* __restrict__ chunk = data + (size_t)b * (cN * cD) + half * (32 * cD);
    float acc[32];
    #pragma unroll
    for (int n = 0; n < 32; ++n) acc[n] = 0.0f;
    for (int dc = 0; dc < cD / 16; ++dc) {
        float pm[16];
        const float4* p4 = reinterpret_cast<const float4*>(projq + t * cD + dc * 16);
        #pragma unroll
        for (int j = 0; j < 4; ++j) {
            float4 v = p4[j];
            float tmp[4] = { v.x, v.y, v.z, v.w };
            #pragma unroll
            for (int e = 0; e < 4; ++e) {
                int d = dc * 16 + j * 4 + e;
                bool msk = (((d < 64) ? (m0 >> d) : (m1 >> (d - 64))) & 1ull) != 0;
                pm[j * 4 + e] = msk ? 0.0f : tmp[e];
            }
        }
        #pragma unroll
        for (int n = 0; n < 32; ++n) {
            const float* __restrict__ r = chunk + n * cD + dc * 16;
            #pragma unroll
            for (int i = 0; i < 16; ++i)
                acc[n] = fmaf(r[i], pm[i], acc[n]);
        }
    }
    #pragma unroll
    for (int n = 0; n < 32; ++n) {
        const int nn = half * 32 + n;
        const float* __restrict__ r = chunk + n * cD;
        float o = 0.0f;
        #pragma unroll
        for (int k = 0; k < cK; ++k)
            o = fmaf((k < U) ? r[ui[k]] : 0.0f, prO[k], o);
        const bool bitIn = acc[n] > 0.0f;
        unsigned long long mIn = __ballot(bitIn);
        unsigned long long mOut = __ballot(o > 0.0f);
        float v = bitIn ? qv : -qv;
        #pragma unroll
        for (int off = 32; off > 0; off >>= 1) v += __shfl_down(v, off);
        if (lane == 0) ipPart[n * 4 + w] = v;
        if (lane < 8) {
            out[(size_t)b * (cN * 32) + nn * 32 + w * 8 + lane] =
                (float)((mIn >> (8 * lane)) & 0xFFull);
            if (w < 2)
                out[HASH_OUT_BASE + (size_t)b * (cN * 16) + nn * 16 + w * 8 + lane] =
                    (float)((mOut >> (8 * lane)) & 0xFFull);
        }
    }
    __syncthreads();
    if (t < 32) {
        float ip = ipPart[t * 4 + 0] + ipPart[t * 4 + 1] + ipPart[t * 4 + 2] + ipPart[t * 4 + 3];
        out[SCORE_BASE + b * cN + half * 32 + t] = 0.0048957583f * norm_data[b * cN + half * 32 + t] * ip;
    }
}

extern "C" void kernel_launch(void* const* d_in, const int* in_sizes, int n_in,
                              void* d_out, int out_size, void* d_ws, size_t ws_size,
                              hipStream_t stream) {
    const float* data      = (const float*)d_in[0];
    const float* query     = (const float*)d_in[1];
    const int*   oidx      = (const int*)d_in[2];
    const float* norm_data = (const float*)d_in[3];
    // d_in[4] = norm_outlier: unused by the reference
    const float* projq     = (const float*)d_in[5];  // proj_dir_quant [S,D]
    const float* projs     = (const float*)d_in[6];  // proj_dir_score [D,S]
    float* out = (float*)d_out;

    if (ws_size >= WS_NEED) {
        float* qv  = (float*)d_ws;
        short* bhi = (short*)((char*)d_ws + WS_BHI);
        short* blo = (short*)((char*)d_ws + WS_BLO);
        qjl_qv<<<cH, cS, 0, stream>>>(query, projs, qv);
        qjl_bfrag<<<16, 256, 0, stream>>>(projq, bhi, blo);
        qjl_mfma<<<cH * cG, 256, 0, stream>>>(data, oidx, norm_data, projq,
                                              qv, bhi, blo, out);
    } else {
        qjl_valu<<<cH * cG * 2, 256, 0, stream>>>(data, query, oidx, norm_data,
                                                  projq, projs, out);
    }
}